// Round 1
// baseline (253.092 us; speedup 1.0000x reference)
//
#include <hip/hip_runtime.h>

// MeanGraphSage: h = relu(concat(x @ Ws, mean_neighbors @ Wn) + bias)
// N=50000 nodes, E=800000 edges, D=64 in-feats, 128 out (64+64 concat).

constexpr int N_NODES = 50000;
constexpr int N_EDGES = 800000;
constexpr int D = 64;
constexpr int UNITS = 128;

// Wave-per-edge scatter: lane d accumulates feature d of x[col]*w into the
// NEIGHBOR HALF of the output buffer (out[row*128 + 64 + d]) so we don't need
// a big workspace. Lane 0 bumps the in-degree count (float, in d_ws).
__global__ __launch_bounds__(256) void sage_scatter(
    const float* __restrict__ x,
    const int*   __restrict__ ei,     // [2, E] row-major: ei[e]=row, ei[E+e]=col
    const float* __restrict__ ew,
    float*       __restrict__ out,    // [N, 128]; we atomically build sums in cols 64..127
    float*       __restrict__ counts) // [N]
{
    const int lane  = threadIdx.x & 63;
    const int wave  = blockIdx.x * (blockDim.x >> 6) + (threadIdx.x >> 6);
    const int nwave = gridDim.x * (blockDim.x >> 6);
    for (int e = wave; e < N_EDGES; e += nwave) {
        const int   row = ei[e];            // target
        const int   col = ei[N_EDGES + e];  // source neighbor
        const float w   = ew[e];
        const float v   = x[col * D + lane] * w;
        atomicAdd(&out[row * UNITS + D + lane], v);
        if (lane == 0) atomicAdd(&counts[row], 1.0f);
    }
}

// Projection: each thread owns one output column j (0..127). Threads j<64 use
// self_kernel on x[n]; threads j>=64 use neighbor_kernel on the mean vector
// (read from the sums we scattered into out[n,64..127], scaled by 1/max(cnt,1)).
// Kernel column lives in registers (loaded coalesced once per block); the
// per-node feature vector is staged in LDS (broadcast reads, conflict-free).
__global__ __launch_bounds__(256) void sage_project(
    const float* __restrict__ x,
    const float* __restrict__ skern,  // [D, 64]
    const float* __restrict__ nkern,  // [D, 64]
    const float* __restrict__ bias,   // [128]
    const float* __restrict__ counts, // [N]
    float*       __restrict__ out)    // [N, 128] in-place
{
    const int tg = threadIdx.x >> 7;        // two 128-thread node-groups per block
    const int j  = threadIdx.x & 127;       // output column
    const int jj = j & (D - 1);
    const float* K = (j < D) ? skern : nkern;

    float kcol[D];
    #pragma unroll
    for (int k = 0; k < D; ++k) kcol[k] = K[k * D + jj];  // coalesced per k
    const float bj = bias[j];
    const int base = (j < D) ? 0 : D;

    __shared__ float feat[2][UNITS];  // [tg][0..63]=x[n], [tg][64..127]=mean[n]

    for (int n = blockIdx.x * 2 + tg; n < N_NODES; n += gridDim.x * 2) {
        if (j < D) {
            feat[tg][j] = x[n * D + j];
        } else {
            const float c   = counts[n];
            const float inv = 1.0f / fmaxf(c, 1.0f);
            feat[tg][j] = out[n * UNITS + j] * inv;   // consume sums
        }
        __syncthreads();
        float acc = 0.0f;
        #pragma unroll
        for (int k = 0; k < D; ++k) acc += feat[tg][base + k] * kcol[k];
        acc += bj;
        out[n * UNITS + j] = fmaxf(acc, 0.0f);        // overwrite (sums consumed)
        __syncthreads();                               // LDS reuse guard
    }
}

extern "C" void kernel_launch(void* const* d_in, const int* in_sizes, int n_in,
                              void* d_out, int out_size, void* d_ws, size_t ws_size,
                              hipStream_t stream) {
    const float* x      = (const float*)d_in[0];
    const int*   ei     = (const int*)  d_in[1];
    const float* ew     = (const float*)d_in[2];
    const float* skern  = (const float*)d_in[3];
    const float* nkern  = (const float*)d_in[4];
    const float* bias   = (const float*)d_in[5];
    float* out    = (float*)d_out;
    float* counts = (float*)d_ws;   // N_NODES floats = 200 KB

    // Zero the accumulation targets every call (deterministic; harness does
    // not re-poison between replays).
    hipMemsetAsync(d_out, 0, (size_t)out_size * sizeof(float), stream);
    hipMemsetAsync(d_ws, 0, (size_t)N_NODES * sizeof(float), stream);

    sage_scatter<<<2048, 256, 0, stream>>>(x, ei, ew, out, counts);
    sage_project<<<2048, 256, 0, stream>>>(x, skern, nkern, bias, counts, out);
}